// Round 1
// baseline (207.640 us; speedup 1.0000x reference)
//
#include <hip/hip_runtime.h>
#include <hip/hip_bf16.h>
#include <math.h>

#define BB 4
#define NN 4096
#define MM 4096
#define DFEA 16
#define JC 8            // j-chunks (grid.y)
#define JTILE 64
#define CHUNK (MM / JC) // 512

// constants
#define INVF 70.71067811865475f   // 1/(sqrt(2)*blur), blur=0.01
#define IB2  10000.0f             // 1/blur^2
#define INV2 5000.0f              // 1/(2*blur^2) = INVF^2

// ws layout in floats
#define WS_YY    0
#define WS_GY2   (WS_YY + BB * MM * DFEA)     // 262144
#define WS_TGT4  (WS_GY2 + BB * MM)           // 278528
#define WS_PART  (WS_TGT4 + BB * MM * 4)      // 344064
#define WS_MOM_F (WS_PART + BB * NN * JC * 5) // 999424 -> byte 3997696 (8B aligned)

// ---------------------------------------------------------------- prep
__global__ __launch_bounds__(256) void prep_kernel(
    const float* __restrict__ tgt_fea, const float* __restrict__ G_j,
    const float* __restrict__ tgt, float* __restrict__ ws) {
  int idx = blockIdx.x * 256 + threadIdx.x; // [0, BB*MM)
  const float4* tf = (const float4*)tgt_fea + (size_t)idx * 4;
  float4 a0 = tf[0], a1 = tf[1], a2 = tf[2], a3 = tf[3];
  a0.x *= INVF; a0.y *= INVF; a0.z *= INVF; a0.w *= INVF;
  a1.x *= INVF; a1.y *= INVF; a1.z *= INVF; a1.w *= INVF;
  a2.x *= INVF; a2.y *= INVF; a2.z *= INVF; a2.w *= INVF;
  a3.x *= INVF; a3.y *= INVF; a3.z *= INVF; a3.w *= INVF;
  float y2 = a0.x*a0.x + a0.y*a0.y + a0.z*a0.z + a0.w*a0.w
           + a1.x*a1.x + a1.y*a1.y + a1.z*a1.z + a1.w*a1.w
           + a2.x*a2.x + a2.y*a2.y + a2.z*a2.z + a2.w*a2.w
           + a3.x*a3.x + a3.y*a3.y + a3.z*a3.z + a3.w*a3.w;
  float4* yy = (float4*)(ws + WS_YY) + (size_t)idx * 4;
  yy[0] = a0; yy[1] = a1; yy[2] = a2; yy[3] = a3;
  ws[WS_GY2 + idx] = G_j[idx] * IB2 - y2;
  float4 t4 = make_float4(tgt[idx*3+0], tgt[idx*3+1], tgt[idx*3+2], 0.f);
  ((float4*)(ws + WS_TGT4))[idx] = t4;
}

// ---------------------------------------------------------------- attention
__global__ __launch_bounds__(256) void attn_kernel(
    const float* __restrict__ src_fea, const float* __restrict__ ws,
    float* __restrict__ partial) {
  __shared__ float  yyt[JTILE][16];
  __shared__ float4 tgts[JTILE];
  __shared__ float  gys[JTILE];
  int tid = threadIdx.x;
  int b = blockIdx.z;
  int i = blockIdx.x * 256 + tid;
  int g = b * NN + i;

  const float4* sf = (const float4*)src_fea + (size_t)g * 4;
  float4 q0 = sf[0], q1 = sf[1], q2 = sf[2], q3 = sf[3];
  q0.x *= INVF; q0.y *= INVF; q0.z *= INVF; q0.w *= INVF;
  q1.x *= INVF; q1.y *= INVF; q1.z *= INVF; q1.w *= INVF;
  q2.x *= INVF; q2.y *= INVF; q2.z *= INVF; q2.w *= INVF;
  q3.x *= INVF; q3.y *= INVF; q3.z *= INVF; q3.w *= INVF;

  const float4* yy   = (const float4*)(ws + WS_YY);
  const float*  gy2  = ws + WS_GY2;
  const float4* tgt4 = (const float4*)(ws + WS_TGT4);
  int col0 = b * MM + blockIdx.y * CHUNK;

  float m = -1e30f, S = 0.f, T0 = 0.f, T1 = 0.f, T2 = 0.f;

  for (int t0 = 0; t0 < CHUNK; t0 += JTILE) {
    __syncthreads();
    {
      int jj = tid >> 2, dd = tid & 3;
      int jcol = col0 + t0 + jj;
      ((float4*)yyt[jj])[dd] = yy[(size_t)jcol * 4 + dd];
      if (tid < JTILE) {
        int jc2 = col0 + t0 + tid;
        tgts[tid] = tgt4[jc2];
        gys[tid]  = gy2[jc2];
      }
    }
    __syncthreads();
    #pragma unroll 8
    for (int jj = 0; jj < JTILE; ++jj) {
      const float4* yr = (const float4*)yyt[jj];
      float4 y0 = yr[0], y1 = yr[1], y2v = yr[2], y3 = yr[3];
      float d0 = fmaf(q0.x, y0.x,  fmaf(q0.y, y0.y,  fmaf(q0.z, y0.z,  q0.w * y0.w)));
      float d1 = fmaf(q1.x, y1.x,  fmaf(q1.y, y1.y,  fmaf(q1.z, y1.z,  q1.w * y1.w)));
      float d2 = fmaf(q2.x, y2v.x, fmaf(q2.y, y2v.y, fmaf(q2.z, y2v.z, q2.w * y2v.w)));
      float d3 = fmaf(q3.x, y3.x,  fmaf(q3.y, y3.y,  fmaf(q3.z, y3.z,  q3.w * y3.w)));
      float s = fmaf(2.f, (d0 + d1) + (d2 + d3), gys[jj]);
      float p;
      if (s > m) {
        float c = __expf(m - s);
        S *= c; T0 *= c; T1 *= c; T2 *= c;
        m = s; p = 1.f;
      } else {
        p = __expf(s - m);
      }
      float4 tg = tgts[jj];
      S += p;
      T0 = fmaf(p, tg.x, T0);
      T1 = fmaf(p, tg.y, T1);
      T2 = fmaf(p, tg.z, T2);
    }
  }
  float* pp = partial + ((size_t)g * JC + blockIdx.y) * 5;
  pp[0] = m; pp[1] = S; pp[2] = T0; pp[3] = T1; pp[4] = T2;
}

// ---------------------------------------------------------------- combine + moments
__global__ __launch_bounds__(256) void combine_kernel(
    const float* __restrict__ partial, const float* __restrict__ src_fea,
    const float* __restrict__ src, const float* __restrict__ F_i,
    double* __restrict__ moments) {
  int b = blockIdx.x, tid = threadIdx.x;
  double acc[23];
  #pragma unroll
  for (int k = 0; k < 23; ++k) acc[k] = 0.0;

  for (int i = tid; i < NN; i += 256) {
    int g = b * NN + i;
    const float* pp = partial + (size_t)g * JC * 5;
    float M = -1e30f;
    #pragma unroll
    for (int c = 0; c < JC; ++c) M = fmaxf(M, pp[c * 5]);
    float S = 0.f, T0 = 0.f, T1 = 0.f, T2 = 0.f;
    #pragma unroll
    for (int c = 0; c < JC; ++c) {
      float e = __expf(pp[c * 5] - M);
      S  = fmaf(pp[c * 5 + 1], e, S);
      T0 = fmaf(pp[c * 5 + 2], e, T0);
      T1 = fmaf(pp[c * 5 + 3], e, T1);
      T2 = fmaf(pp[c * 5 + 4], e, T2);
    }
    float invS = 1.f / S;
    float y0 = T0 * invS, y1 = T1 * invS, y2 = T2 * invS;

    const float4* sfp = (const float4*)src_fea + (size_t)g * 4;
    float4 a0 = sfp[0], a1 = sfp[1], a2 = sfp[2], a3 = sfp[3];
    float ss = a0.x*a0.x + a0.y*a0.y + a0.z*a0.z + a0.w*a0.w
             + a1.x*a1.x + a1.y*a1.y + a1.z*a1.z + a1.w*a1.w
             + a2.x*a2.x + a2.y*a2.y + a2.z*a2.z + a2.w*a2.w
             + a3.x*a3.x + a3.y*a3.y + a3.z*a3.z + a3.w*a3.w;
    float x2 = ss * INV2;
    float w = __expf(F_i[g] * IB2 - x2 + M) * S;

    float px = src[(size_t)g * 3 + 0];
    float py = src[(size_t)g * 3 + 1];
    float pz = src[(size_t)g * 3 + 2];

    double wd = (double)w, w2 = wd * wd;
    acc[0]  += wd;
    acc[1]  += wd * px;  acc[2]  += wd * py;  acc[3]  += wd * pz;
    acc[4]  += wd * y0;  acc[5]  += wd * y1;  acc[6]  += wd * y2;
    acc[7]  += w2;
    acc[8]  += w2 * px;  acc[9]  += w2 * py;  acc[10] += w2 * pz;
    acc[11] += w2 * y0;  acc[12] += w2 * y1;  acc[13] += w2 * y2;
    acc[14] += w2 * y0 * px; acc[15] += w2 * y0 * py; acc[16] += w2 * y0 * pz;
    acc[17] += w2 * y1 * px; acc[18] += w2 * y1 * py; acc[19] += w2 * y1 * pz;
    acc[20] += w2 * y2 * px; acc[21] += w2 * y2 * py; acc[22] += w2 * y2 * pz;
  }

  __shared__ double red[256][23];
  #pragma unroll
  for (int k = 0; k < 23; ++k) red[tid][k] = acc[k];
  __syncthreads();
  for (int s = 128; s > 0; s >>= 1) {
    if (tid < s) {
      #pragma unroll
      for (int k = 0; k < 23; ++k) red[tid][k] += red[tid + s][k];
    }
    __syncthreads();
  }
  if (tid == 0) {
    #pragma unroll
    for (int k = 0; k < 23; ++k) moments[b * 23 + k] = red[0][k];
  }
}

// ---------------------------------------------------------------- finalize (SVD)
__device__ __forceinline__ double det3(const double M[3][3]) {
  return M[0][0] * (M[1][1] * M[2][2] - M[1][2] * M[2][1])
       - M[0][1] * (M[1][0] * M[2][2] - M[1][2] * M[2][0])
       + M[0][2] * (M[1][0] * M[2][1] - M[1][1] * M[2][0]);
}

__global__ void finalize_kernel(const double* __restrict__ moments,
                                float* __restrict__ out) {
  int b = threadIdx.x;
  if (b >= BB) return;
  const double* mo = moments + b * 23;
  double sw = mo[0];
  double mux[3] = { mo[1] / sw, mo[2] / sw, mo[3] / sw };
  double muy[3] = { mo[4] / sw, mo[5] / sw, mo[6] / sw };
  double sw2 = mo[7];
  double A[3][3];
  for (int d = 0; d < 3; ++d)
    for (int e = 0; e < 3; ++e)
      A[d][e] = mo[14 + d * 3 + e] - muy[d] * mo[8 + e] - mux[e] * mo[11 + d]
              + sw2 * muy[d] * mux[e];

  // ATA = A^T A
  double ATA[3][3];
  for (int p = 0; p < 3; ++p)
    for (int q = 0; q < 3; ++q)
      ATA[p][q] = A[0][p] * A[0][q] + A[1][p] * A[1][q] + A[2][p] * A[2][q];

  double V[3][3] = { {1,0,0}, {0,1,0}, {0,0,1} };
  for (int sweep = 0; sweep < 25; ++sweep) {
    for (int pair = 0; pair < 3; ++pair) {
      int p = (pair == 2) ? 1 : 0;
      int q = (pair == 0) ? 1 : 2;
      double apq = ATA[p][q];
      if (fabs(apq) < 1e-300) continue;
      double tau = (ATA[q][q] - ATA[p][p]) / (2.0 * apq);
      double tt = ((tau >= 0.0) ? 1.0 : -1.0) / (fabs(tau) + sqrt(1.0 + tau * tau));
      double c = 1.0 / sqrt(1.0 + tt * tt), sn = tt * c;
      for (int k = 0; k < 3; ++k) {
        double akp = ATA[k][p], akq = ATA[k][q];
        ATA[k][p] = c * akp - sn * akq;
        ATA[k][q] = sn * akp + c * akq;
      }
      for (int k = 0; k < 3; ++k) {
        double apk = ATA[p][k], aqk = ATA[q][k];
        ATA[p][k] = c * apk - sn * aqk;
        ATA[q][k] = sn * apk + c * aqk;
      }
      for (int k = 0; k < 3; ++k) {
        double vkp = V[k][p], vkq = V[k][q];
        V[k][p] = c * vkp - sn * vkq;
        V[k][q] = sn * vkp + c * vkq;
      }
    }
  }

  double U[3][3];
  for (int k = 0; k < 3; ++k) {
    double sv = sqrt(fmax(ATA[k][k], 0.0));
    double u0 = A[0][0] * V[0][k] + A[0][1] * V[1][k] + A[0][2] * V[2][k];
    double u1 = A[1][0] * V[0][k] + A[1][1] * V[1][k] + A[1][2] * V[2][k];
    double u2 = A[2][0] * V[0][k] + A[2][1] * V[1][k] + A[2][2] * V[2][k];
    double inv = (sv > 1e-300) ? 1.0 / sv : 0.0;
    U[0][k] = u0 * inv; U[1][k] = u1 * inv; U[2][k] = u2 * inv;
  }

  double dd = det3(U) * det3(V); // = det(u @ v), ±1
  // Q = U V^T ; r = diag(1,1,dd) @ Q  (reference scales last ROW of u)
  double R[3][3];
  for (int d = 0; d < 3; ++d)
    for (int e = 0; e < 3; ++e)
      R[d][e] = U[d][0] * V[e][0] + U[d][1] * V[e][1] + U[d][2] * V[e][2];
  R[2][0] *= dd; R[2][1] *= dd; R[2][2] *= dd;

  double tr[3];
  for (int d = 0; d < 3; ++d)
    tr[d] = muy[d] - (R[d][0] * mux[0] + R[d][1] * mux[1] + R[d][2] * mux[2]);

  for (int d = 0; d < 3; ++d)
    for (int e = 0; e < 3; ++e)
      out[b * 9 + d * 3 + e] = (float)R[d][e];
  out[BB * 9 + b * 3 + 0] = (float)tr[0];
  out[BB * 9 + b * 3 + 1] = (float)tr[1];
  out[BB * 9 + b * 3 + 2] = (float)tr[2];
}

// ---------------------------------------------------------------- launch
extern "C" void kernel_launch(void* const* d_in, const int* in_sizes, int n_in,
                              void* d_out, int out_size, void* d_ws, size_t ws_size,
                              hipStream_t stream) {
  const float* src     = (const float*)d_in[0];
  const float* tgt     = (const float*)d_in[1];
  const float* src_fea = (const float*)d_in[2];
  const float* tgt_fea = (const float*)d_in[3];
  const float* F_i     = (const float*)d_in[4];
  const float* G_j     = (const float*)d_in[5];
  float* ws  = (float*)d_ws;
  float* out = (float*)d_out;
  double* moments = (double*)(ws + WS_MOM_F);

  prep_kernel<<<BB * MM / 256, 256, 0, stream>>>(tgt_fea, G_j, tgt, ws);
  dim3 grid(NN / 256, JC, BB);
  attn_kernel<<<grid, 256, 0, stream>>>(src_fea, ws, ws + WS_PART);
  combine_kernel<<<BB, 256, 0, stream>>>(ws + WS_PART, src_fea, src, F_i, moments);
  finalize_kernel<<<1, 64, 0, stream>>>(moments, out);
}

// Round 2
// 159.764 us; speedup vs baseline: 1.2997x; 1.2997x over previous
//
#include <hip/hip_runtime.h>
#include <hip/hip_bf16.h>
#include <math.h>

#define BB 4
#define NN 4096
#define MM 4096
#define JC 32           // j-chunks (grid.y)
#define CHUNK (MM / JC) // 128
#define JTILE 64

#define INVF  70.71067811865475f   // 1/(sqrt(2)*blur)
#define IB2   10000.0f             // 1/blur^2
#define INV2  5000.0f              // INVF^2
#define LOG2E 1.4426950408889634f
#define LN2   0.6931471805599453f

// ws layout in floats
#define WS_YY   0                          // BB*MM*16 : yy_s = tgt_fea*INVF*2*LOG2E
#define WS_GYL  (WS_YY + BB*MM*16)         // BB*MM    : LOG2E*(G_j/b^2 - ||yy||^2)
#define WS_Y2S  (WS_GYL + BB*MM)           // BB*MM    : ||yy_s||^2
#define WS_TGT4 (WS_Y2S + BB*MM)           // BB*MM*4
#define WS_BND  (WS_TGT4 + BB*MM*4)        // BB*2 : [gmaxl, ymaxs]
#define WS_PART (WS_BND + 8)               // BB*NN*JC*4  (16B-aligned: 360456*4%16==0)
#define WS_BLK  (WS_PART + BB*NN*JC*4)     // 64*23 doubles

// ---------------------------------------------------------------- prep
__global__ __launch_bounds__(256) void prep_kernel(
    const float* __restrict__ tgt_fea, const float* __restrict__ G_j,
    const float* __restrict__ tgt, float* __restrict__ ws) {
  int idx = blockIdx.x * 256 + threadIdx.x; // [0, BB*MM)
  const float4* tf = (const float4*)tgt_fea + (size_t)idx * 4;
  float4 a[4];
  float y2n = 0.f;
  #pragma unroll
  for (int k = 0; k < 4; ++k) {
    a[k] = tf[k];
    a[k].x *= INVF; a[k].y *= INVF; a[k].z *= INVF; a[k].w *= INVF;
    y2n += a[k].x*a[k].x + a[k].y*a[k].y + a[k].z*a[k].z + a[k].w*a[k].w;
  }
  const float SC = 2.f * LOG2E;
  float4* yy = (float4*)(ws + WS_YY) + (size_t)idx * 4;
  #pragma unroll
  for (int k = 0; k < 4; ++k) {
    float4 s = a[k];
    s.x *= SC; s.y *= SC; s.z *= SC; s.w *= SC;
    yy[k] = s;
  }
  ws[WS_GYL + idx] = LOG2E * (G_j[idx] * IB2 - y2n);
  ws[WS_Y2S + idx] = y2n * SC * SC;
  float4 t4 = make_float4(tgt[idx*3+0], tgt[idx*3+1], tgt[idx*3+2], 0.f);
  ((float4*)(ws + WS_TGT4))[idx] = t4;
}

// ---------------------------------------------------------------- bounds (per batch maxes)
__global__ __launch_bounds__(256) void bounds_kernel(float* __restrict__ ws) {
  int b = blockIdx.x, tid = threadIdx.x;
  float m1 = -1e30f, m2 = 0.f;
  for (int j = tid; j < MM; j += 256) {
    m1 = fmaxf(m1, ws[WS_GYL + b * MM + j]);
    m2 = fmaxf(m2, ws[WS_Y2S + b * MM + j]);
  }
  __shared__ float r1[256], r2[256];
  r1[tid] = m1; r2[tid] = m2;
  __syncthreads();
  for (int s = 128; s > 0; s >>= 1) {
    if (tid < s) { r1[tid] = fmaxf(r1[tid], r1[tid+s]); r2[tid] = fmaxf(r2[tid], r2[tid+s]); }
    __syncthreads();
  }
  if (tid == 0) {
    ws[WS_BND + b * 2 + 0] = r1[0];
    ws[WS_BND + b * 2 + 1] = sqrtf(r2[0]);
  }
}

// ---------------------------------------------------------------- attention
__global__ __launch_bounds__(256, 8) void attn_kernel(
    const float* __restrict__ src_fea, const float* __restrict__ ws,
    float* __restrict__ partial) {
  __shared__ float  yyt[JTILE][16];
  __shared__ float4 tgts[JTILE];
  __shared__ float  gys[JTILE];
  int tid = threadIdx.x;
  int b = blockIdx.z;
  int i = blockIdx.x * 256 + tid;
  int g = b * NN + i;

  const float4* sf = (const float4*)src_fea + (size_t)g * 4;
  float4 q0 = sf[0], q1 = sf[1], q2 = sf[2], q3 = sf[3];
  q0.x *= INVF; q0.y *= INVF; q0.z *= INVF; q0.w *= INVF;
  q1.x *= INVF; q1.y *= INVF; q1.z *= INVF; q1.w *= INVF;
  q2.x *= INVF; q2.y *= INVF; q2.z *= INVF; q2.w *= INVF;
  q3.x *= INVF; q3.y *= INVF; q3.z *= INVF; q3.w *= INVF;
  float x2 = q0.x*q0.x + q0.y*q0.y + q0.z*q0.z + q0.w*q0.w
           + q1.x*q1.x + q1.y*q1.y + q1.z*q1.z + q1.w*q1.w
           + q2.x*q2.x + q2.y*q2.y + q2.z*q2.z + q2.w*q2.w
           + q3.x*q3.x + q3.y*q3.y + q3.z*q3.z + q3.w*q3.w;
  float gmaxl = ws[WS_BND + b * 2 + 0];
  float ymaxs = ws[WS_BND + b * 2 + 1];
  float mrowl = gmaxl + sqrtf(x2) * ymaxs;      // bound on d in log2 units
  float pm    = __builtin_amdgcn_exp2f(-mrowl); // common scale for this row

  const float4* yy   = (const float4*)(ws + WS_YY);
  const float*  gyl  = ws + WS_GYL;
  const float4* tgt4 = (const float4*)(ws + WS_TGT4);
  int col0 = b * MM + blockIdx.y * CHUNK;

  float S = 0.f, T0 = 0.f, T1 = 0.f, T2 = 0.f;

  for (int t0 = 0; t0 < CHUNK; t0 += JTILE) {
    __syncthreads();
    {
      int jj = tid >> 2, dd = tid & 3;
      int jcol = col0 + t0 + jj;
      ((float4*)yyt[jj])[dd] = yy[(size_t)jcol * 4 + dd];
      if (tid < JTILE) {
        int jc2 = col0 + t0 + tid;
        tgts[tid] = tgt4[jc2];
        gys[tid]  = gyl[jc2];
      }
    }
    __syncthreads();
    #pragma unroll 8
    for (int jj = 0; jj < JTILE; ++jj) {
      const float4* yr = (const float4*)yyt[jj];
      float4 y0 = yr[0], y1 = yr[1], y2v = yr[2], y3 = yr[3];
      // d = gys + q . yy_s   (= log2e * s_ij), bounded above by mrowl
      float d0 = fmaf(q0.x, y0.x,  fmaf(q0.y, y0.y,  fmaf(q0.z, y0.z,  fmaf(q0.w, y0.w, gys[jj]))));
      float d1 = fmaf(q1.x, y1.x,  fmaf(q1.y, y1.y,  fmaf(q1.z, y1.z,  q1.w * y1.w)));
      float d2 = fmaf(q2.x, y2v.x, fmaf(q2.y, y2v.y, fmaf(q2.z, y2v.z, q2.w * y2v.w)));
      float d3 = fmaf(q3.x, y3.x,  fmaf(q3.y, y3.y,  fmaf(q3.z, y3.z,  q3.w * y3.w)));
      float p = __builtin_amdgcn_exp2f((d0 + d1) + (d2 + d3));
      float4 tg = tgts[jj];
      S += p;
      T0 = fmaf(p, tg.x, T0);
      T1 = fmaf(p, tg.y, T1);
      T2 = fmaf(p, tg.z, T2);
    }
  }
  float4 res = make_float4(S * pm, T0 * pm, T1 * pm, T2 * pm);
  ((float4*)partial)[(size_t)g * JC + blockIdx.y] = res;
}

// ---------------------------------------------------------------- combine (one thread per row)
__global__ __launch_bounds__(256) void combine_kernel(
    const float* __restrict__ partial, const float* __restrict__ src_fea,
    const float* __restrict__ src, const float* __restrict__ F_i,
    const float* __restrict__ ws, double* __restrict__ blockpart) {
  int b = blockIdx.x, xb = blockIdx.y, tid = threadIdx.x;
  int i = xb * 256 + tid;
  int g = b * NN + i;

  const float4* pr = (const float4*)partial + (size_t)g * JC;
  float S = 0.f, T0 = 0.f, T1 = 0.f, T2 = 0.f;
  #pragma unroll
  for (int c = 0; c < JC; ++c) {
    float4 v = pr[c];
    S += v.x; T0 += v.y; T1 += v.z; T2 += v.w;
  }
  float invS = 1.f / S;
  float y0 = T0 * invS, y1 = T1 * invS, y2 = T2 * invS;

  const float4* sfp = (const float4*)src_fea + (size_t)g * 4;
  float4 a0 = sfp[0], a1 = sfp[1], a2 = sfp[2], a3 = sfp[3];
  a0.x*=INVF; a0.y*=INVF; a0.z*=INVF; a0.w*=INVF;
  a1.x*=INVF; a1.y*=INVF; a1.z*=INVF; a1.w*=INVF;
  a2.x*=INVF; a2.y*=INVF; a2.z*=INVF; a2.w*=INVF;
  a3.x*=INVF; a3.y*=INVF; a3.z*=INVF; a3.w*=INVF;
  float x2 = a0.x*a0.x + a0.y*a0.y + a0.z*a0.z + a0.w*a0.w
           + a1.x*a1.x + a1.y*a1.y + a1.z*a1.z + a1.w*a1.w
           + a2.x*a2.x + a2.y*a2.y + a2.z*a2.z + a2.w*a2.w
           + a3.x*a3.x + a3.y*a3.y + a3.z*a3.z + a3.w*a3.w;
  float gmaxl = ws[WS_BND + b * 2 + 0];
  float ymaxs = ws[WS_BND + b * 2 + 1];
  float mrowl = gmaxl + sqrtf(x2) * ymaxs;
  // w = exp(f' - x2 + lse),  lse(log2) = mrowl + log2(S)
  float w = __builtin_amdgcn_exp2f((F_i[g] * IB2 - x2) * LOG2E + mrowl
                                   + __builtin_amdgcn_logf(S));

  float px = src[(size_t)g * 3 + 0];
  float py = src[(size_t)g * 3 + 1];
  float pz = src[(size_t)g * 3 + 2];

  double acc[23];
  double wd = (double)w, w2 = wd * wd;
  acc[0]  = wd;
  acc[1]  = wd * px;  acc[2]  = wd * py;  acc[3]  = wd * pz;
  acc[4]  = wd * y0;  acc[5]  = wd * y1;  acc[6]  = wd * y2;
  acc[7]  = w2;
  acc[8]  = w2 * px;  acc[9]  = w2 * py;  acc[10] = w2 * pz;
  acc[11] = w2 * y0;  acc[12] = w2 * y1;  acc[13] = w2 * y2;
  acc[14] = w2 * y0 * px; acc[15] = w2 * y0 * py; acc[16] = w2 * y0 * pz;
  acc[17] = w2 * y1 * px; acc[18] = w2 * y1 * py; acc[19] = w2 * y1 * pz;
  acc[20] = w2 * y2 * px; acc[21] = w2 * y2 * py; acc[22] = w2 * y2 * pz;

  __shared__ double red[256][23];
  #pragma unroll
  for (int k = 0; k < 23; ++k) red[tid][k] = acc[k];
  __syncthreads();
  for (int s = 128; s > 0; s >>= 1) {
    if (tid < s) {
      #pragma unroll
      for (int k = 0; k < 23; ++k) red[tid][k] += red[tid + s][k];
    }
    __syncthreads();
  }
  if (tid == 0) {
    #pragma unroll
    for (int k = 0; k < 23; ++k) blockpart[((size_t)b * 16 + xb) * 23 + k] = red[0][k];
  }
}

// ---------------------------------------------------------------- finalize (SVD)
__device__ __forceinline__ double det3(const double M[3][3]) {
  return M[0][0] * (M[1][1] * M[2][2] - M[1][2] * M[2][1])
       - M[0][1] * (M[1][0] * M[2][2] - M[1][2] * M[2][0])
       + M[0][2] * (M[1][0] * M[2][1] - M[1][1] * M[2][0]);
}

__global__ void finalize_kernel(const double* __restrict__ blockpart,
                                float* __restrict__ out) {
  int b = threadIdx.x;
  if (b >= BB) return;
  double mo[23];
  #pragma unroll
  for (int k = 0; k < 23; ++k) mo[k] = 0.0;
  for (int xb = 0; xb < 16; ++xb)
    #pragma unroll
    for (int k = 0; k < 23; ++k) mo[k] += blockpart[((size_t)b * 16 + xb) * 23 + k];

  double sw = mo[0];
  double mux[3] = { mo[1] / sw, mo[2] / sw, mo[3] / sw };
  double muy[3] = { mo[4] / sw, mo[5] / sw, mo[6] / sw };
  double sw2 = mo[7];
  double A[3][3];
  for (int d = 0; d < 3; ++d)
    for (int e = 0; e < 3; ++e)
      A[d][e] = mo[14 + d * 3 + e] - muy[d] * mo[8 + e] - mux[e] * mo[11 + d]
              + sw2 * muy[d] * mux[e];

  double ATA[3][3];
  for (int p = 0; p < 3; ++p)
    for (int q = 0; q < 3; ++q)
      ATA[p][q] = A[0][p] * A[0][q] + A[1][p] * A[1][q] + A[2][p] * A[2][q];

  double V[3][3] = { {1,0,0}, {0,1,0}, {0,0,1} };
  for (int sweep = 0; sweep < 12; ++sweep) {
    for (int pair = 0; pair < 3; ++pair) {
      int p = (pair == 2) ? 1 : 0;
      int q = (pair == 0) ? 1 : 2;
      double apq = ATA[p][q];
      if (fabs(apq) < 1e-300) continue;
      double tau = (ATA[q][q] - ATA[p][p]) / (2.0 * apq);
      double tt = ((tau >= 0.0) ? 1.0 : -1.0) / (fabs(tau) + sqrt(1.0 + tau * tau));
      double c = 1.0 / sqrt(1.0 + tt * tt), sn = tt * c;
      for (int k = 0; k < 3; ++k) {
        double akp = ATA[k][p], akq = ATA[k][q];
        ATA[k][p] = c * akp - sn * akq;
        ATA[k][q] = sn * akp + c * akq;
      }
      for (int k = 0; k < 3; ++k) {
        double apk = ATA[p][k], aqk = ATA[q][k];
        ATA[p][k] = c * apk - sn * aqk;
        ATA[q][k] = sn * apk + c * aqk;
      }
      for (int k = 0; k < 3; ++k) {
        double vkp = V[k][p], vkq = V[k][q];
        V[k][p] = c * vkp - sn * vkq;
        V[k][q] = sn * vkp + c * vkq;
      }
    }
  }

  double U[3][3];
  for (int k = 0; k < 3; ++k) {
    double sv = sqrt(fmax(ATA[k][k], 0.0));
    double u0 = A[0][0] * V[0][k] + A[0][1] * V[1][k] + A[0][2] * V[2][k];
    double u1 = A[1][0] * V[0][k] + A[1][1] * V[1][k] + A[1][2] * V[2][k];
    double u2 = A[2][0] * V[0][k] + A[2][1] * V[1][k] + A[2][2] * V[2][k];
    double inv = (sv > 1e-300) ? 1.0 / sv : 0.0;
    U[0][k] = u0 * inv; U[1][k] = u1 * inv; U[2][k] = u2 * inv;
  }

  double dd = det3(U) * det3(V);
  double R[3][3];
  for (int d = 0; d < 3; ++d)
    for (int e = 0; e < 3; ++e)
      R[d][e] = U[d][0] * V[e][0] + U[d][1] * V[e][1] + U[d][2] * V[e][2];
  R[2][0] *= dd; R[2][1] *= dd; R[2][2] *= dd;

  double tr[3];
  for (int d = 0; d < 3; ++d)
    tr[d] = muy[d] - (R[d][0] * mux[0] + R[d][1] * mux[1] + R[d][2] * mux[2]);

  for (int d = 0; d < 3; ++d)
    for (int e = 0; e < 3; ++e)
      out[b * 9 + d * 3 + e] = (float)R[d][e];
  out[BB * 9 + b * 3 + 0] = (float)tr[0];
  out[BB * 9 + b * 3 + 1] = (float)tr[1];
  out[BB * 9 + b * 3 + 2] = (float)tr[2];
}

// ---------------------------------------------------------------- launch
extern "C" void kernel_launch(void* const* d_in, const int* in_sizes, int n_in,
                              void* d_out, int out_size, void* d_ws, size_t ws_size,
                              hipStream_t stream) {
  const float* src     = (const float*)d_in[0];
  const float* tgt     = (const float*)d_in[1];
  const float* src_fea = (const float*)d_in[2];
  const float* tgt_fea = (const float*)d_in[3];
  const float* F_i     = (const float*)d_in[4];
  const float* G_j     = (const float*)d_in[5];
  float* ws  = (float*)d_ws;
  float* out = (float*)d_out;
  double* blockpart = (double*)(ws + WS_BLK);

  prep_kernel<<<BB * MM / 256, 256, 0, stream>>>(tgt_fea, G_j, tgt, ws);
  bounds_kernel<<<BB, 256, 0, stream>>>(ws);
  dim3 grid(NN / 256, JC, BB);
  attn_kernel<<<grid, 256, 0, stream>>>(src_fea, ws, ws + WS_PART);
  dim3 cgrid(BB, 16);
  combine_kernel<<<cgrid, 256, 0, stream>>>(ws + WS_PART, src_fea, src, F_i, ws, blockpart);
  finalize_kernel<<<1, 64, 0, stream>>>(blockpart, out);
}

// Round 3
// 138.329 us; speedup vs baseline: 1.5011x; 1.1550x over previous
//
#include <hip/hip_runtime.h>
#include <hip/hip_bf16.h>
#include <math.h>

#define BB 4
#define NN 4096
#define MM 4096
#define JC 32           // j-chunks (grid.y)
#define CHUNK (MM / JC) // 128 == one LDS tile

#define INVF  70.71067811865475f   // 1/(sqrt(2)*blur)
#define IB2   10000.0f             // 1/blur^2
#define LOG2E 1.4426950408889634f

// ws layout in floats
#define WS_YY   0                          // BB*MM*16 : yy_s = tgt_fea*INVF*2*LOG2E
#define WS_TG4  (WS_YY + BB*MM*16)         // BB*MM*4  : (tgt.xyz, gyl)
#define WS_PART (WS_TG4 + BB*MM*4)         // BB*NN*JC*4 floats (8.4 MB)
#define WS_BLK  (WS_PART + BB*NN*JC*4)     // 64*23 doubles

// ---------------------------------------------------------------- prep
__global__ __launch_bounds__(256) void prep_kernel(
    const float* __restrict__ tgt_fea, const float* __restrict__ G_j,
    const float* __restrict__ tgt, float* __restrict__ ws) {
  int idx = blockIdx.x * 256 + threadIdx.x; // [0, BB*MM)
  const float4* tf = (const float4*)tgt_fea + (size_t)idx * 4;
  float4 a[4];
  float y2n = 0.f;
  #pragma unroll
  for (int k = 0; k < 4; ++k) {
    a[k] = tf[k];
    a[k].x *= INVF; a[k].y *= INVF; a[k].z *= INVF; a[k].w *= INVF;
    y2n += a[k].x*a[k].x + a[k].y*a[k].y + a[k].z*a[k].z + a[k].w*a[k].w;
  }
  const float SC = 2.f * LOG2E;
  float4* yy = (float4*)(ws + WS_YY) + (size_t)idx * 4;
  #pragma unroll
  for (int k = 0; k < 4; ++k) {
    float4 s = a[k];
    s.x *= SC; s.y *= SC; s.z *= SC; s.w *= SC;
    yy[k] = s;
  }
  float gyl = LOG2E * (G_j[idx] * IB2 - y2n);
  float4 t4 = make_float4(tgt[idx*3+0], tgt[idx*3+1], tgt[idx*3+2], gyl);
  ((float4*)(ws + WS_TG4))[idx] = t4;
}

// ---------------------------------------------------------------- attention (R=2 rows/thread)
__global__ __launch_bounds__(256, 4) void attn_kernel(
    const float* __restrict__ src_fea, const float* __restrict__ ws,
    float* __restrict__ partial) {
  __shared__ float  yyt[CHUNK][16];
  __shared__ float4 tg4s[CHUNK];
  int tid = threadIdx.x;
  int b = blockIdx.z;
  int iA = blockIdx.x * 512 + tid;
  int iB = iA + 256;
  int gA = b * NN + iA, gB = b * NN + iB;

  // load + scale both rows' queries (scale INVF; yy carries the 2*log2e)
  const float4* sfA = (const float4*)src_fea + (size_t)gA * 4;
  const float4* sfB = (const float4*)src_fea + (size_t)gB * 4;
  float4 qa0 = sfA[0], qa1 = sfA[1], qa2 = sfA[2], qa3 = sfA[3];
  float4 qb0 = sfB[0], qb1 = sfB[1], qb2 = sfB[2], qb3 = sfB[3];
  qa0.x*=INVF; qa0.y*=INVF; qa0.z*=INVF; qa0.w*=INVF;
  qa1.x*=INVF; qa1.y*=INVF; qa1.z*=INVF; qa1.w*=INVF;
  qa2.x*=INVF; qa2.y*=INVF; qa2.z*=INVF; qa2.w*=INVF;
  qa3.x*=INVF; qa3.y*=INVF; qa3.z*=INVF; qa3.w*=INVF;
  qb0.x*=INVF; qb0.y*=INVF; qb0.z*=INVF; qb0.w*=INVF;
  qb1.x*=INVF; qb1.y*=INVF; qb1.z*=INVF; qb1.w*=INVF;
  qb2.x*=INVF; qb2.y*=INVF; qb2.z*=INVF; qb2.w*=INVF;
  qb3.x*=INVF; qb3.y*=INVF; qb3.z*=INVF; qb3.w*=INVF;

  int col0 = b * MM + blockIdx.y * CHUNK;
  // stage the whole chunk once
  {
    const float4* yy = (const float4*)(ws + WS_YY);
    #pragma unroll
    for (int r = 0; r < 2; ++r) {
      int e = tid + r * 256;            // [0,512): row=e>>2, comp=e&3
      ((float4*)yyt[e >> 2])[e & 3] = yy[(size_t)(col0 + (e >> 2)) * 4 + (e & 3)];
    }
    if (tid < CHUNK)
      tg4s[tid] = ((const float4*)(ws + WS_TG4))[col0 + tid];
  }
  __syncthreads();

  float SA = 0.f, TA0 = 0.f, TA1 = 0.f, TA2 = 0.f;
  float SB = 0.f, TB0 = 0.f, TB1 = 0.f, TB2 = 0.f;

  #pragma unroll 4
  for (int jj = 0; jj < CHUNK; ++jj) {
    const float4* yr = (const float4*)yyt[jj];
    float4 y0 = yr[0], y1 = yr[1], y2 = yr[2], y3 = yr[3];
    float4 tg = tg4s[jj];                    // tg.w = gyl
    float dA0 = fmaf(qa0.x, y0.x, fmaf(qa0.y, y0.y, fmaf(qa0.z, y0.z, fmaf(qa0.w, y0.w, tg.w))));
    float dA1 = fmaf(qa1.x, y1.x, fmaf(qa1.y, y1.y, fmaf(qa1.z, y1.z, qa1.w * y1.w)));
    float dA2 = fmaf(qa2.x, y2.x, fmaf(qa2.y, y2.y, fmaf(qa2.z, y2.z, qa2.w * y2.w)));
    float dA3 = fmaf(qa3.x, y3.x, fmaf(qa3.y, y3.y, fmaf(qa3.z, y3.z, qa3.w * y3.w)));
    float dB0 = fmaf(qb0.x, y0.x, fmaf(qb0.y, y0.y, fmaf(qb0.z, y0.z, fmaf(qb0.w, y0.w, tg.w))));
    float dB1 = fmaf(qb1.x, y1.x, fmaf(qb1.y, y1.y, fmaf(qb1.z, y1.z, qb1.w * y1.w)));
    float dB2 = fmaf(qb2.x, y2.x, fmaf(qb2.y, y2.y, fmaf(qb2.z, y2.z, qb2.w * y2.w)));
    float dB3 = fmaf(qb3.x, y3.x, fmaf(qb3.y, y3.y, fmaf(qb3.z, y3.z, qb3.w * y3.w)));
    float pA = __builtin_amdgcn_exp2f((dA0 + dA1) + (dA2 + dA3));
    float pB = __builtin_amdgcn_exp2f((dB0 + dB1) + (dB2 + dB3));
    SA += pA;
    TA0 = fmaf(pA, tg.x, TA0); TA1 = fmaf(pA, tg.y, TA1); TA2 = fmaf(pA, tg.z, TA2);
    SB += pB;
    TB0 = fmaf(pB, tg.x, TB0); TB1 = fmaf(pB, tg.y, TB1); TB2 = fmaf(pB, tg.z, TB2);
  }
  ((float4*)partial)[(size_t)gA * JC + blockIdx.y] = make_float4(SA, TA0, TA1, TA2);
  ((float4*)partial)[(size_t)gB * JC + blockIdx.y] = make_float4(SB, TB0, TB1, TB2);
}

// ---------------------------------------------------------------- combine (one thread per row)
__global__ __launch_bounds__(256) void combine_kernel(
    const float* __restrict__ partial, const float* __restrict__ src_fea,
    const float* __restrict__ src, const float* __restrict__ F_i,
    double* __restrict__ blockpart) {
  int b = blockIdx.x, xb = blockIdx.y, tid = threadIdx.x;
  int i = xb * 256 + tid;
  int g = b * NN + i;

  const float4* pr = (const float4*)partial + (size_t)g * JC;
  float S = 0.f, T0 = 0.f, T1 = 0.f, T2 = 0.f;
  #pragma unroll
  for (int c = 0; c < JC; ++c) {
    float4 v = pr[c];
    S += v.x; T0 += v.y; T1 += v.z; T2 += v.w;
  }
  float invS = 1.f / S;
  float y0 = T0 * invS, y1 = T1 * invS, y2 = T2 * invS;

  const float4* sfp = (const float4*)src_fea + (size_t)g * 4;
  float4 a0 = sfp[0], a1 = sfp[1], a2 = sfp[2], a3 = sfp[3];
  a0.x*=INVF; a0.y*=INVF; a0.z*=INVF; a0.w*=INVF;
  a1.x*=INVF; a1.y*=INVF; a1.z*=INVF; a1.w*=INVF;
  a2.x*=INVF; a2.y*=INVF; a2.z*=INVF; a2.w*=INVF;
  a3.x*=INVF; a3.y*=INVF; a3.z*=INVF; a3.w*=INVF;
  float x2 = a0.x*a0.x + a0.y*a0.y + a0.z*a0.z + a0.w*a0.w
           + a1.x*a1.x + a1.y*a1.y + a1.z*a1.z + a1.w*a1.w
           + a2.x*a2.x + a2.y*a2.y + a2.z*a2.z + a2.w*a2.w
           + a3.x*a3.x + a3.y*a3.y + a3.z*a3.z + a3.w*a3.w;
  // w = exp(f' - x2 + lse) ; in log2: (f'-x2)*log2e + log2(S)
  float w = __builtin_amdgcn_exp2f((F_i[g] * IB2 - x2) * LOG2E
                                   + __builtin_amdgcn_logf(S));

  float px = src[(size_t)g * 3 + 0];
  float py = src[(size_t)g * 3 + 1];
  float pz = src[(size_t)g * 3 + 2];

  double acc[23];
  double wd = (double)w, w2 = wd * wd;
  acc[0]  = wd;
  acc[1]  = wd * px;  acc[2]  = wd * py;  acc[3]  = wd * pz;
  acc[4]  = wd * y0;  acc[5]  = wd * y1;  acc[6]  = wd * y2;
  acc[7]  = w2;
  acc[8]  = w2 * px;  acc[9]  = w2 * py;  acc[10] = w2 * pz;
  acc[11] = w2 * y0;  acc[12] = w2 * y1;  acc[13] = w2 * y2;
  acc[14] = w2 * y0 * px; acc[15] = w2 * y0 * py; acc[16] = w2 * y0 * pz;
  acc[17] = w2 * y1 * px; acc[18] = w2 * y1 * py; acc[19] = w2 * y1 * pz;
  acc[20] = w2 * y2 * px; acc[21] = w2 * y2 * py; acc[22] = w2 * y2 * pz;

  // wave-level reduction (64 lanes)
  #pragma unroll
  for (int k = 0; k < 23; ++k) {
    #pragma unroll
    for (int off = 32; off > 0; off >>= 1)
      acc[k] += __shfl_down(acc[k], off, 64);
  }
  __shared__ double red[4][23];
  int wave = tid >> 6, lane = tid & 63;
  if (lane == 0) {
    #pragma unroll
    for (int k = 0; k < 23; ++k) red[wave][k] = acc[k];
  }
  __syncthreads();
  if (tid < 23) {
    double s = red[0][tid] + red[1][tid] + red[2][tid] + red[3][tid];
    blockpart[((size_t)b * 16 + xb) * 23 + tid] = s;
  }
}

// ---------------------------------------------------------------- finalize (SVD)
__device__ __forceinline__ double det3(const double M[3][3]) {
  return M[0][0] * (M[1][1] * M[2][2] - M[1][2] * M[2][1])
       - M[0][1] * (M[1][0] * M[2][2] - M[1][2] * M[2][0])
       + M[0][2] * (M[1][0] * M[2][1] - M[1][1] * M[2][0]);
}

__global__ void finalize_kernel(const double* __restrict__ blockpart,
                                float* __restrict__ out) {
  int b = threadIdx.x;
  if (b >= BB) return;
  double mo[23];
  #pragma unroll
  for (int k = 0; k < 23; ++k) mo[k] = 0.0;
  for (int xb = 0; xb < 16; ++xb)
    #pragma unroll
    for (int k = 0; k < 23; ++k) mo[k] += blockpart[((size_t)b * 16 + xb) * 23 + k];

  double sw = mo[0];
  double mux[3] = { mo[1] / sw, mo[2] / sw, mo[3] / sw };
  double muy[3] = { mo[4] / sw, mo[5] / sw, mo[6] / sw };
  double sw2 = mo[7];
  double A[3][3];
  for (int d = 0; d < 3; ++d)
    for (int e = 0; e < 3; ++e)
      A[d][e] = mo[14 + d * 3 + e] - muy[d] * mo[8 + e] - mux[e] * mo[11 + d]
              + sw2 * muy[d] * mux[e];

  double ATA[3][3];
  for (int p = 0; p < 3; ++p)
    for (int q = 0; q < 3; ++q)
      ATA[p][q] = A[0][p] * A[0][q] + A[1][p] * A[1][q] + A[2][p] * A[2][q];

  double V[3][3] = { {1,0,0}, {0,1,0}, {0,0,1} };
  for (int sweep = 0; sweep < 12; ++sweep) {
    for (int pair = 0; pair < 3; ++pair) {
      int p = (pair == 2) ? 1 : 0;
      int q = (pair == 0) ? 1 : 2;
      double apq = ATA[p][q];
      if (fabs(apq) < 1e-300) continue;
      double tau = (ATA[q][q] - ATA[p][p]) / (2.0 * apq);
      double tt = ((tau >= 0.0) ? 1.0 : -1.0) / (fabs(tau) + sqrt(1.0 + tau * tau));
      double c = 1.0 / sqrt(1.0 + tt * tt), sn = tt * c;
      for (int k = 0; k < 3; ++k) {
        double akp = ATA[k][p], akq = ATA[k][q];
        ATA[k][p] = c * akp - sn * akq;
        ATA[k][q] = sn * akp + c * akq;
      }
      for (int k = 0; k < 3; ++k) {
        double apk = ATA[p][k], aqk = ATA[q][k];
        ATA[p][k] = c * apk - sn * aqk;
        ATA[q][k] = sn * apk + c * aqk;
      }
      for (int k = 0; k < 3; ++k) {
        double vkp = V[k][p], vkq = V[k][q];
        V[k][p] = c * vkp - sn * vkq;
        V[k][q] = sn * vkp + c * vkq;
      }
    }
  }

  double U[3][3];
  for (int k = 0; k < 3; ++k) {
    double sv = sqrt(fmax(ATA[k][k], 0.0));
    double u0 = A[0][0] * V[0][k] + A[0][1] * V[1][k] + A[0][2] * V[2][k];
    double u1 = A[1][0] * V[0][k] + A[1][1] * V[1][k] + A[1][2] * V[2][k];
    double u2 = A[2][0] * V[0][k] + A[2][1] * V[1][k] + A[2][2] * V[2][k];
    double inv = (sv > 1e-300) ? 1.0 / sv : 0.0;
    U[0][k] = u0 * inv; U[1][k] = u1 * inv; U[2][k] = u2 * inv;
  }

  double dd = det3(U) * det3(V);
  double R[3][3];
  for (int d = 0; d < 3; ++d)
    for (int e = 0; e < 3; ++e)
      R[d][e] = U[d][0] * V[e][0] + U[d][1] * V[e][1] + U[d][2] * V[e][2];
  R[2][0] *= dd; R[2][1] *= dd; R[2][2] *= dd;

  double tr[3];
  for (int d = 0; d < 3; ++d)
    tr[d] = muy[d] - (R[d][0] * mux[0] + R[d][1] * mux[1] + R[d][2] * mux[2]);

  for (int d = 0; d < 3; ++d)
    for (int e = 0; e < 3; ++e)
      out[b * 9 + d * 3 + e] = (float)R[d][e];
  out[BB * 9 + b * 3 + 0] = (float)tr[0];
  out[BB * 9 + b * 3 + 1] = (float)tr[1];
  out[BB * 9 + b * 3 + 2] = (float)tr[2];
}

// ---------------------------------------------------------------- launch
extern "C" void kernel_launch(void* const* d_in, const int* in_sizes, int n_in,
                              void* d_out, int out_size, void* d_ws, size_t ws_size,
                              hipStream_t stream) {
  const float* src     = (const float*)d_in[0];
  const float* tgt     = (const float*)d_in[1];
  const float* src_fea = (const float*)d_in[2];
  const float* tgt_fea = (const float*)d_in[3];
  const float* F_i     = (const float*)d_in[4];
  const float* G_j     = (const float*)d_in[5];
  float* ws  = (float*)d_ws;
  float* out = (float*)d_out;
  double* blockpart = (double*)(ws + WS_BLK);

  prep_kernel<<<BB * MM / 256, 256, 0, stream>>>(tgt_fea, G_j, tgt, ws);
  dim3 grid(NN / 512, JC, BB);
  attn_kernel<<<grid, 256, 0, stream>>>(src_fea, ws, ws + WS_PART);
  dim3 cgrid(BB, 16);
  combine_kernel<<<cgrid, 256, 0, stream>>>(ws + WS_PART, src_fea, src, F_i, blockpart);
  finalize_kernel<<<1, 64, 0, stream>>>(blockpart, out);
}